// Round 6
// baseline (161.142 us; speedup 1.0000x reference)
//
#include <hip/hip_runtime.h>
#include <hip/hip_bf16.h>

typedef __attribute__((ext_vector_type(8))) _Float16 hfx8;
typedef __attribute__((ext_vector_type(2))) __fp16 fp16x2;
typedef __attribute__((ext_vector_type(4))) float fx4;
typedef __attribute__((ext_vector_type(4))) unsigned short usx4;

#define LOG2E 1.44269504f

__device__ __forceinline__ unsigned short f2h(float f) {
  union { _Float16 h; unsigned short u; } c;
  c.h = (_Float16)f;
  return c.u;
}

__device__ __forceinline__ void async16(const void* g, void* l) {
  __builtin_amdgcn_global_load_lds(
      (const __attribute__((address_space(1))) void*)g,
      (__attribute__((address_space(3))) void*)l, 16, 0, 0);
}

// f32 -> fp16, 1024 elements per block
__global__ __launch_bounds__(256)
void cvth(const float* __restrict__ s, unsigned short* __restrict__ d) {
  int i = (blockIdx.x * 256 + threadIdx.x) * 4;
  fx4 v = *(const fx4*)(s + i);
  usx4 o;
  o[0] = f2h(v[0]); o[1] = f2h(v[1]); o[2] = f2h(v[2]); o[3] = f2h(v[3]);
  *(usx4*)(d + i) = o;
}

// 4 weight matrices f32 -> fp16; grid.y selects
__global__ __launch_bounds__(256)
void cvtw(const float* __restrict__ s0, const float* __restrict__ s1,
          const float* __restrict__ s2, const float* __restrict__ s3,
          unsigned short* __restrict__ d0, unsigned short* __restrict__ d1,
          unsigned short* __restrict__ d2, unsigned short* __restrict__ d3) {
  const int y = blockIdx.y;
  const float* s = (y == 0) ? s0 : (y == 1) ? s1 : (y == 2) ? s2 : s3;
  unsigned short* d = (y == 0) ? d0 : (y == 1) ? d1 : (y == 2) ? d2 : d3;
  int i = (blockIdx.x * 256 + threadIdx.x) * 4;
  fx4 v = *(const fx4*)(s + i);
  usx4 o;
  o[0] = f2h(v[0]); o[1] = f2h(v[1]); o[2] = f2h(v[2]); o[3] = f2h(v[3]);
  *(usx4*)(d + i) = o;
}

// QKV projection fp16: C[m][n] = sum_k A[m][k]*W[n][k], K=1024.
// grid (32, 24): sel = by>>3 (0=Q flat *ATT_SCALE, 1=K flat, 2=V -> V^T store).
// Double-buffered LDS, prefetch next K-tile before compute.
__global__ __launch_bounds__(256, 2)
void gemm_qkv(const unsigned short* __restrict__ A,
              const unsigned short* __restrict__ Wq,
              const unsigned short* __restrict__ Wk,
              const unsigned short* __restrict__ Wv,
              unsigned short* __restrict__ Qf, unsigned short* __restrict__ Kf,
              unsigned short* __restrict__ Vt) {
  __shared__ unsigned short As[2][128 * 64];
  __shared__ unsigned short Bs[2][128 * 64];
  const int tid = threadIdx.x;
  const int w = tid >> 6, ln = tid & 63;
  const int mt = blockIdx.x;
  const int by = blockIdx.y;
  const int sel = by >> 3;
  const int nt = by & 7;
  const unsigned short* W = (sel == 0) ? Wq : ((sel == 1) ? Wk : Wv);
  const int m0 = mt * 128, n0 = nt * 128;
  const int wr = w >> 1, wc = w & 1;
  fx4 acc[4][4] = {};

  const int lr = ln >> 3;
  const int scg = (ln & 7) ^ lr;
  const unsigned short* Asrc = A + (size_t)(m0 + w * 32 + lr) * 1024 + scg * 8;
  const unsigned short* Bsrc = W + (size_t)(n0 + w * 32 + lr) * 1024 + scg * 8;

#define G_STAGE(KT, BI)                                                        \
  {                                                                            \
    _Pragma("unroll") for (int i = 0; i < 4; ++i) {                            \
      async16(Asrc + (size_t)i * 8 * 1024 + (KT) * 64, &As[BI][(w * 32 + i * 8) * 64]); \
      async16(Bsrc + (size_t)i * 8 * 1024 + (KT) * 64, &Bs[BI][(w * 32 + i * 8) * 64]); \
    }                                                                          \
  }

  G_STAGE(0, 0);
  for (int kt = 0; kt < 16; ++kt) {
    const int cur = kt & 1;
    __syncthreads();
    if (kt < 15) G_STAGE(kt + 1, cur ^ 1);
#pragma unroll
    for (int kk = 0; kk < 2; ++kk) {
      const int kg = kk * 4 + (ln >> 4);
      hfx8 af[4], bfr[4];
#pragma unroll
      for (int mi = 0; mi < 4; ++mi) {
        int row = wr * 64 + mi * 16 + (ln & 15);
        af[mi] = *(const hfx8*)&As[cur][row * 64 + ((kg ^ (row & 7)) * 8)];
      }
#pragma unroll
      for (int ni = 0; ni < 4; ++ni) {
        int row = wc * 64 + ni * 16 + (ln & 15);
        bfr[ni] = *(const hfx8*)&Bs[cur][row * 64 + ((kg ^ (row & 7)) * 8)];
      }
#pragma unroll
      for (int mi = 0; mi < 4; ++mi)
#pragma unroll
        for (int ni = 0; ni < 4; ++ni)
          acc[mi][ni] = __builtin_amdgcn_mfma_f32_16x16x32_f16(af[mi], bfr[ni], acc[mi][ni], 0, 0, 0);
    }
  }
#undef G_STAGE
  const int cb = n0 + wc * 64 + (ln & 15);
  const int rb = m0 + wr * 64 + ((ln >> 4) << 2);
  if (sel < 2) {
    unsigned short* O = sel ? Kf : Qf;
    const float sc = sel ? 1.0f : 0.125f;  // fold ATT_SCALE into Q
#pragma unroll
    for (int mi = 0; mi < 4; ++mi)
#pragma unroll
      for (int ni = 0; ni < 4; ++ni)
#pragma unroll
        for (int j = 0; j < 4; ++j)
          O[(size_t)(rb + mi * 16 + j) * 1024 + cb + ni * 16] = f2h(acc[mi][ni][j] * sc);
  } else {
    // V^T: Vt[((b*16+h)*64+d)][s], 4 consecutive s per lane -> usx4
#pragma unroll
    for (int mi = 0; mi < 4; ++mi)
#pragma unroll
      for (int ni = 0; ni < 4; ++ni) {
        int s0 = rb + mi * 16;
        int c = cb + ni * 16;
        int bI = s0 >> 11, s = s0 & 2047;
        int hh = c >> 6, dd = c & 63;
        usx4 pk;
#pragma unroll
        for (int j = 0; j < 4; ++j) pk[j] = f2h(acc[mi][ni][j]);
        *(usx4*)&Vt[((size_t)(bI * 16 + hh) * 64 + dd) * 2048 + s] = pk;
      }
  }
}

// O-projection fp16: C = A[4096][1024] * W^T, f32 out; dbuf prefetch
__global__ __launch_bounds__(256, 2)
void gemm_o(const unsigned short* __restrict__ A,
            const unsigned short* __restrict__ W,
            float* __restrict__ O) {
  __shared__ unsigned short As[2][128 * 64];
  __shared__ unsigned short Bs[2][128 * 64];
  const int tid = threadIdx.x;
  const int w = tid >> 6, ln = tid & 63;
  const int mt = blockIdx.x, nt = blockIdx.y;
  const int m0 = mt * 128, n0 = nt * 128;
  const int wr = w >> 1, wc = w & 1;
  fx4 acc[4][4] = {};
  const int lr = ln >> 3;
  const int scg = (ln & 7) ^ lr;
  const unsigned short* Asrc = A + (size_t)(m0 + w * 32 + lr) * 1024 + scg * 8;
  const unsigned short* Bsrc = W + (size_t)(n0 + w * 32 + lr) * 1024 + scg * 8;

#define G_STAGE(KT, BI)                                                        \
  {                                                                            \
    _Pragma("unroll") for (int i = 0; i < 4; ++i) {                            \
      async16(Asrc + (size_t)i * 8 * 1024 + (KT) * 64, &As[BI][(w * 32 + i * 8) * 64]); \
      async16(Bsrc + (size_t)i * 8 * 1024 + (KT) * 64, &Bs[BI][(w * 32 + i * 8) * 64]); \
    }                                                                          \
  }

  G_STAGE(0, 0);
  for (int kt = 0; kt < 16; ++kt) {
    const int cur = kt & 1;
    __syncthreads();
    if (kt < 15) G_STAGE(kt + 1, cur ^ 1);
#pragma unroll
    for (int kk = 0; kk < 2; ++kk) {
      const int kg = kk * 4 + (ln >> 4);
      hfx8 af[4], bfr[4];
#pragma unroll
      for (int mi = 0; mi < 4; ++mi) {
        int row = wr * 64 + mi * 16 + (ln & 15);
        af[mi] = *(const hfx8*)&As[cur][row * 64 + ((kg ^ (row & 7)) * 8)];
      }
#pragma unroll
      for (int ni = 0; ni < 4; ++ni) {
        int row = wc * 64 + ni * 16 + (ln & 15);
        bfr[ni] = *(const hfx8*)&Bs[cur][row * 64 + ((kg ^ (row & 7)) * 8)];
      }
#pragma unroll
      for (int mi = 0; mi < 4; ++mi)
#pragma unroll
        for (int ni = 0; ni < 4; ++ni)
          acc[mi][ni] = __builtin_amdgcn_mfma_f32_16x16x32_f16(af[mi], bfr[ni], acc[mi][ni], 0, 0, 0);
    }
  }
#undef G_STAGE
  const int cb = n0 + wc * 64 + (ln & 15);
  const int rb = m0 + wr * 64 + ((ln >> 4) << 2);
#pragma unroll
  for (int mi = 0; mi < 4; ++mi)
#pragma unroll
    for (int ni = 0; ni < 4; ++ni)
#pragma unroll
      for (int j = 0; j < 4; ++j)
        O[(size_t)(rb + mi * 16 + j) * 1024 + cb + ni * 16] = acc[mi][ni][j];
}

// Flash attention fp16, swapped QK^T; double-buffered K/V; mask folded into
// the QK accumulator init; defer-max (THR=8); native exp2; cvt_pkrtz packing.
// block = (qt,h,b); 8 waves x 16 q-rows = 128 q-rows; K-tile = 128.
__global__ __launch_bounds__(512, 4)
void attn_fwd(const unsigned short* __restrict__ Qf,
              const unsigned short* __restrict__ Kf,
              const unsigned short* __restrict__ Vt,
              const int* __restrict__ mask,
              unsigned short* __restrict__ Ov) {
  __shared__ unsigned short Ks[2][128 * 64];
  __shared__ unsigned short Vs[2][64 * 128];
  __shared__ float mfAll[2048];
  const int tid = threadIdx.x;
  const int w = tid >> 6, ln = tid & 63;
  const int qt = blockIdx.x, h = blockIdx.y, b = blockIdx.z;
  const int q0 = qt * 128;
  const int g = ln >> 4, qy = ln & 15;

  // Q as B-fragment: lane holds Q[q0 + w*16 + qy][dims kk*32 + g*8 + 0..7]
  hfx8 qf[2];
  {
    int q = q0 + w * 16 + qy;
    size_t off = (size_t)(b * 2048 + q) * 1024 + h * 64 + g * 8;
    qf[0] = *(const hfx8*)(Qf + off);
    qf[1] = *(const hfx8*)(Qf + off + 32);
  }
  fx4 o[4] = {};
  float mrow = -INFINITY, lrow = 0.f;

  const int lr = ln >> 3;
  const int scg = (ln & 7) ^ lr;
  const unsigned short* Ksrc = Kf + (size_t)(b * 2048 + w * 16 + lr) * 1024 + h * 64 + scg * 8;
  const unsigned short* Vbase = Vt + (size_t)(b * 16 + h) * 64 * 2048;

  // preload mask -> additive floats (once per block)
  {
    int i4 = tid * 4;
    const int* mp = mask + b * 2048 + i4;
#pragma unroll
    for (int j = 0; j < 4; ++j)
      mfAll[i4 + j] = (mp[j] == 0) ? -1e30f : 0.0f;
  }

#define A_STAGE(KT, BI)                                                        \
  {                                                                            \
    _Pragma("unroll") for (int i = 0; i < 2; ++i)                              \
        async16(Ksrc + (size_t)((KT) * 128 + i * 8) * 1024,                    \
                &Ks[BI][(w * 16 + i * 8) * 64]);                               \
    _Pragma("unroll") for (int i = 0; i < 2; ++i) {                            \
      int d = w * 8 + i * 4 + g;                                               \
      async16(Vbase + (size_t)d * 2048 + (KT) * 128 + ((qy ^ (d & 7)) * 8),    \
              &Vs[BI][(w * 8 + i * 4) * 128]);                                 \
    }                                                                          \
  }

  A_STAGE(0, 0);
  for (int kt = 0; kt < 16; ++kt) {
    const int cur = kt & 1;
    __syncthreads();
    if (kt < 15) A_STAGE(kt + 1, cur ^ 1);

    // S^T = K Q^T (Q pre-scaled): C[key = ni*16 + g*4 + j][q = qy], C-init = mask
    fx4 s[8];
    __builtin_amdgcn_s_setprio(1);
#pragma unroll
    for (int ni = 0; ni < 8; ++ni) {
      fx4 z = *(const fx4*)&mfAll[kt * 128 + ni * 16 + g * 4];
#pragma unroll
      for (int kk = 0; kk < 2; ++kk) {
        int row = ni * 16 + qy;
        int kg = kk * 4 + g;
        hfx8 kf = *(const hfx8*)&Ks[cur][row * 64 + ((kg ^ (row & 7)) * 8)];
        z = __builtin_amdgcn_mfma_f32_16x16x32_f16(kf, qf[kk], z, 0, 0, 0);
      }
      s[ni] = z;
    }
    __builtin_amdgcn_s_setprio(0);

    // per-q (lane-local) online softmax with defer-max
    float tm = -INFINITY;
#pragma unroll
    for (int ni = 0; ni < 8; ++ni)
#pragma unroll
      for (int j = 0; j < 4; ++j)
        tm = fmaxf(tm, s[ni][j]);
    tm = fmaxf(tm, __shfl_xor(tm, 16));
    tm = fmaxf(tm, __shfl_xor(tm, 32));
    if (!__all(tm <= mrow + 8.0f)) {
      float mn = fmaxf(mrow, tm);
      float fac = exp2f((mrow - mn) * LOG2E);
      mrow = mn;
      lrow *= fac;
      float facj[4];
#pragma unroll
      for (int j = 0; j < 4; ++j) facj[j] = __shfl(fac, g * 4 + j);
#pragma unroll
      for (int di = 0; di < 4; ++di)
#pragma unroll
        for (int j = 0; j < 4; ++j)
          o[di][j] *= facj[j];
    }
    const float nm2 = -mrow * LOG2E;
    float psum = 0.f;
    unsigned int wA[8], wB[8];
#pragma unroll
    for (int ni = 0; ni < 8; ++ni) {
      float p0 = exp2f(fmaf(s[ni][0], LOG2E, nm2));
      float p1 = exp2f(fmaf(s[ni][1], LOG2E, nm2));
      float p2 = exp2f(fmaf(s[ni][2], LOG2E, nm2));
      float p3 = exp2f(fmaf(s[ni][3], LOG2E, nm2));
      psum += (p0 + p1) + (p2 + p3);
      union { fp16x2 h; unsigned int u; } r0, r1;
      r0.h = __builtin_amdgcn_cvt_pkrtz(p0, p1);
      r1.h = __builtin_amdgcn_cvt_pkrtz(p2, p3);
      wA[ni] = r0.u;
      wB[ni] = r1.u;
    }
    psum += __shfl_xor(psum, 16);
    psum += __shfl_xor(psum, 32);
    lrow += psum;

    // P -> A-frag transpose in-register, then O += P V
#pragma unroll
    for (int kk = 0; kk < 4; ++kk) {
      const int F0 = 2 * kk, F1 = F0 + 1;
      const int srcA = ((2 * g) & 3) * 16 + qy;
      const int srcB = srcA + 16;
      unsigned int a0 = __shfl(wA[F0], srcA), a1 = __shfl(wA[F1], srcA);
      unsigned int b0 = __shfl(wB[F0], srcA), b1 = __shfl(wB[F1], srcA);
      unsigned int c0 = __shfl(wA[F0], srcB), c1 = __shfl(wA[F1], srcB);
      unsigned int e0 = __shfl(wB[F0], srcB), e1 = __shfl(wB[F1], srcB);
      const bool hi = g >= 2;
      union { unsigned int u[4]; hfx8 v; } pu;
      pu.u[0] = hi ? a1 : a0;
      pu.u[1] = hi ? b1 : b0;
      pu.u[2] = hi ? c1 : c0;
      pu.u[3] = hi ? e1 : e0;
      const int pg = kk * 4 + g;
      __builtin_amdgcn_s_setprio(1);
#pragma unroll
      for (int di = 0; di < 4; ++di) {
        int vrow = di * 16 + qy;
        hfx8 vb = *(const hfx8*)&Vs[cur][vrow * 128 + ((pg ^ (vrow & 7)) * 8)];
        o[di] = __builtin_amdgcn_mfma_f32_16x16x32_f16(pu.v, vb, o[di], 0, 0, 0);
      }
      __builtin_amdgcn_s_setprio(0);
    }
  }
#undef A_STAGE
  float lrj[4];
#pragma unroll
  for (int j = 0; j < 4; ++j) lrj[j] = __shfl(lrow, g * 4 + j);
#pragma unroll
  for (int di = 0; di < 4; ++di)
#pragma unroll
    for (int j = 0; j < 4; ++j) {
      int sq_ = q0 + w * 16 + g * 4 + j;
      float v = o[di][j] / lrj[j];
      Ov[(size_t)(b * 2048 + sq_) * 1024 + h * 64 + di * 16 + qy] = f2h(v);
    }
}

// out = LayerNorm(h + attn_out) * g + b ; one block per row
__global__ __launch_bounds__(256)
void lnk(const float* __restrict__ h, const float* __restrict__ ao,
         const float* __restrict__ g, const float* __restrict__ bb,
         float* __restrict__ out) {
  const int row = blockIdx.x;
  const int tid = threadIdx.x;
  const size_t base = (size_t)row * 1024 + tid * 4;
  fx4 x = *(const fx4*)(h + base);
  fx4 a = *(const fx4*)(ao + base);
  x = x + a;
  float s = x[0] + x[1] + x[2] + x[3];
  float q = x[0] * x[0] + x[1] * x[1] + x[2] * x[2] + x[3] * x[3];
#pragma unroll
  for (int mm = 1; mm < 64; mm <<= 1) {
    s += __shfl_xor(s, mm);
    q += __shfl_xor(q, mm);
  }
  __shared__ float rs[4], rq[4];
  if ((tid & 63) == 0) { rs[tid >> 6] = s; rq[tid >> 6] = q; }
  __syncthreads();
  s = rs[0] + rs[1] + rs[2] + rs[3];
  q = rq[0] + rq[1] + rq[2] + rq[3];
  float mu = s * (1.0f / 1024.0f);
  float var = q * (1.0f / 1024.0f) - mu * mu;
  float rstd = rsqrtf(var + 1e-5f);
  fx4 gg = *(const fx4*)(g + tid * 4);
  fx4 bv = *(const fx4*)(bb + tid * 4);
  fx4 ov;
#pragma unroll
  for (int k = 0; k < 4; ++k) ov[k] = (x[k] - mu) * rstd * gg[k] + bv[k];
  *(fx4*)(out + base) = ov;
}

extern "C" void kernel_launch(void* const* d_in, const int* in_sizes, int n_in,
                              void* d_out, int out_size, void* d_ws, size_t ws_size,
                              hipStream_t stream) {
  const float* h = (const float*)d_in[0];
  const int* msk = (const int*)d_in[1];
  const float* qw = (const float*)d_in[2];
  const float* kw = (const float*)d_in[3];
  const float* vw = (const float*)d_in[4];
  const float* ow = (const float*)d_in[5];
  const float* lng = (const float*)d_in[6];
  const float* lnb = (const float*)d_in[7];
  float* out = (float*)d_out;
  char* ws = (char*)d_ws;

  const size_t MB = 1u << 20;
  unsigned short* h16 = (unsigned short*)(ws + 0 * MB);   // 8 MB
  unsigned short* w16q = (unsigned short*)(ws + 8 * MB);  // 2 MB
  unsigned short* w16k = (unsigned short*)(ws + 10 * MB); // 2 MB
  unsigned short* w16v = (unsigned short*)(ws + 12 * MB); // 2 MB
  unsigned short* w16o = (unsigned short*)(ws + 14 * MB); // 2 MB
  unsigned short* Qf  = (unsigned short*)(ws + 16 * MB);  // 8 MB
  unsigned short* Kf  = (unsigned short*)(ws + 24 * MB);  // 8 MB
  unsigned short* Vtb = (unsigned short*)(ws + 32 * MB);  // 8 MB
  unsigned short* Av  = (unsigned short*)(ws + 40 * MB);  // 8 MB
  float* Ao = (float*)(ws + 48 * MB);                     // 16 MB

  cvth<<<dim3(4096), 256, 0, stream>>>(h, h16);
  cvtw<<<dim3(1024, 4), 256, 0, stream>>>(qw, kw, vw, ow, w16q, w16k, w16v, w16o);

  gemm_qkv<<<dim3(32, 24), 256, 0, stream>>>(h16, w16q, w16k, w16v, Qf, Kf, Vtb);
  attn_fwd<<<dim3(16, 16, 2), 512, 0, stream>>>(Qf, Kf, Vtb, msk, Av);
  gemm_o<<<dim3(32, 8), 256, 0, stream>>>(Av, w16o, Ao);
  lnk<<<dim3(4096), 256, 0, stream>>>(h, Ao, lng, lnb, out);
}

// Round 9
// 151.036 us; speedup vs baseline: 1.0669x; 1.0669x over previous
//
#include <hip/hip_runtime.h>
#include <hip/hip_bf16.h>

typedef __attribute__((ext_vector_type(8))) _Float16 hfx8;
typedef __attribute__((ext_vector_type(16))) float fx16;
typedef __attribute__((ext_vector_type(2))) __fp16 fp16x2;
typedef __attribute__((ext_vector_type(4))) float fx4;
typedef __attribute__((ext_vector_type(4))) unsigned short usx4;
typedef __attribute__((ext_vector_type(8))) unsigned short usx8;
typedef __attribute__((ext_vector_type(2))) unsigned int ux2;

#define LOG2E 1.44269504f

__device__ __forceinline__ unsigned short f2h(float f) {
  union { _Float16 h; unsigned short u; } c;
  c.h = (_Float16)f;
  return c.u;
}

__device__ __forceinline__ void async16(const void* g, void* l) {
  __builtin_amdgcn_global_load_lds(
      (const __attribute__((address_space(1))) void*)g,
      (__attribute__((address_space(3))) void*)l, 16, 0, 0);
}

// f32 -> fp16, 1024 elements per block
__global__ __launch_bounds__(256)
void cvth(const float* __restrict__ s, unsigned short* __restrict__ d) {
  int i = (blockIdx.x * 256 + threadIdx.x) * 4;
  fx4 v = *(const fx4*)(s + i);
  usx4 o;
  o[0] = f2h(v[0]); o[1] = f2h(v[1]); o[2] = f2h(v[2]); o[3] = f2h(v[3]);
  *(usx4*)(d + i) = o;
}

// 4 weight matrices f32 -> fp16; grid.y selects
__global__ __launch_bounds__(256)
void cvtw(const float* __restrict__ s0, const float* __restrict__ s1,
          const float* __restrict__ s2, const float* __restrict__ s3,
          unsigned short* __restrict__ d0, unsigned short* __restrict__ d1,
          unsigned short* __restrict__ d2, unsigned short* __restrict__ d3) {
  const int y = blockIdx.y;
  const float* s = (y == 0) ? s0 : (y == 1) ? s1 : (y == 2) ? s2 : s3;
  unsigned short* d = (y == 0) ? d0 : (y == 1) ? d1 : (y == 2) ? d2 : d3;
  int i = (blockIdx.x * 256 + threadIdx.x) * 4;
  fx4 v = *(const fx4*)(s + i);
  usx4 o;
  o[0] = f2h(v[0]); o[1] = f2h(v[1]); o[2] = f2h(v[2]); o[3] = f2h(v[3]);
  *(usx4*)(d + i) = o;
}

// QKV projection fp16: C[m][n] = sum_k A[m][k]*W[n][k], K=1024.
// grid (32, 24): sel = by>>3 (0=Q flat *ATT_SCALE, 1=K flat, 2=V -> V^T store).
__global__ __launch_bounds__(256, 2)
void gemm_qkv(const unsigned short* __restrict__ A,
              const unsigned short* __restrict__ Wq,
              const unsigned short* __restrict__ Wk,
              const unsigned short* __restrict__ Wv,
              unsigned short* __restrict__ Qf, unsigned short* __restrict__ Kf,
              unsigned short* __restrict__ Vt) {
  __shared__ unsigned short As[2][128 * 64];
  __shared__ unsigned short Bs[2][128 * 64];
  const int tid = threadIdx.x;
  const int w = tid >> 6, ln = tid & 63;
  const int mt = blockIdx.x;
  const int by = blockIdx.y;
  const int sel = by >> 3;
  const int nt = by & 7;
  const unsigned short* W = (sel == 0) ? Wq : ((sel == 1) ? Wk : Wv);
  const int m0 = mt * 128, n0 = nt * 128;
  const int wr = w >> 1, wc = w & 1;
  fx4 acc[4][4] = {};

  const int lr = ln >> 3;
  const int scg = (ln & 7) ^ lr;
  const unsigned short* Asrc = A + (size_t)(m0 + w * 32 + lr) * 1024 + scg * 8;
  const unsigned short* Bsrc = W + (size_t)(n0 + w * 32 + lr) * 1024 + scg * 8;

#define G_STAGE(KT, BI)                                                        \
  {                                                                            \
    _Pragma("unroll") for (int i = 0; i < 4; ++i) {                            \
      async16(Asrc + (size_t)i * 8 * 1024 + (KT) * 64, &As[BI][(w * 32 + i * 8) * 64]); \
      async16(Bsrc + (size_t)i * 8 * 1024 + (KT) * 64, &Bs[BI][(w * 32 + i * 8) * 64]); \
    }                                                                          \
  }

  G_STAGE(0, 0);
  for (int kt = 0; kt < 16; ++kt) {
    const int cur = kt & 1;
    __syncthreads();
    if (kt < 15) G_STAGE(kt + 1, cur ^ 1);
#pragma unroll
    for (int kk = 0; kk < 2; ++kk) {
      const int kg = kk * 4 + (ln >> 4);
      hfx8 af[4], bfr[4];
#pragma unroll
      for (int mi = 0; mi < 4; ++mi) {
        int row = wr * 64 + mi * 16 + (ln & 15);
        af[mi] = *(const hfx8*)&As[cur][row * 64 + ((kg ^ (row & 7)) * 8)];
      }
#pragma unroll
      for (int ni = 0; ni < 4; ++ni) {
        int row = wc * 64 + ni * 16 + (ln & 15);
        bfr[ni] = *(const hfx8*)&Bs[cur][row * 64 + ((kg ^ (row & 7)) * 8)];
      }
#pragma unroll
      for (int mi = 0; mi < 4; ++mi)
#pragma unroll
        for (int ni = 0; ni < 4; ++ni)
          acc[mi][ni] = __builtin_amdgcn_mfma_f32_16x16x32_f16(af[mi], bfr[ni], acc[mi][ni], 0, 0, 0);
    }
  }
#undef G_STAGE
  const int cb = n0 + wc * 64 + (ln & 15);
  const int rb = m0 + wr * 64 + ((ln >> 4) << 2);
  if (sel < 2) {
    unsigned short* O = sel ? Kf : Qf;
    const float sc = sel ? 1.0f : 0.125f;  // fold ATT_SCALE into Q
#pragma unroll
    for (int mi = 0; mi < 4; ++mi)
#pragma unroll
      for (int ni = 0; ni < 4; ++ni)
#pragma unroll
        for (int j = 0; j < 4; ++j)
          O[(size_t)(rb + mi * 16 + j) * 1024 + cb + ni * 16] = f2h(acc[mi][ni][j] * sc);
  } else {
    // V^T: Vt[((b*16+h)*64+d)][s], 4 consecutive s per lane -> usx4
#pragma unroll
    for (int mi = 0; mi < 4; ++mi)
#pragma unroll
      for (int ni = 0; ni < 4; ++ni) {
        int s0 = rb + mi * 16;
        int c = cb + ni * 16;
        int bI = s0 >> 11, s = s0 & 2047;
        int hh = c >> 6, dd = c & 63;
        usx4 pk;
#pragma unroll
        for (int j = 0; j < 4; ++j) pk[j] = f2h(acc[mi][ni][j]);
        *(usx4*)&Vt[((size_t)(bI * 16 + hh) * 64 + dd) * 2048 + s] = pk;
      }
  }
}

// O-projection fp16: C = A[4096][1024] * W^T, f32 out; dbuf prefetch
__global__ __launch_bounds__(256, 2)
void gemm_o(const unsigned short* __restrict__ A,
            const unsigned short* __restrict__ W,
            float* __restrict__ O) {
  __shared__ unsigned short As[2][128 * 64];
  __shared__ unsigned short Bs[2][128 * 64];
  const int tid = threadIdx.x;
  const int w = tid >> 6, ln = tid & 63;
  const int mt = blockIdx.x, nt = blockIdx.y;
  const int m0 = mt * 128, n0 = nt * 128;
  const int wr = w >> 1, wc = w & 1;
  fx4 acc[4][4] = {};
  const int lr = ln >> 3;
  const int scg = (ln & 7) ^ lr;
  const unsigned short* Asrc = A + (size_t)(m0 + w * 32 + lr) * 1024 + scg * 8;
  const unsigned short* Bsrc = W + (size_t)(n0 + w * 32 + lr) * 1024 + scg * 8;

#define G_STAGE(KT, BI)                                                        \
  {                                                                            \
    _Pragma("unroll") for (int i = 0; i < 4; ++i) {                            \
      async16(Asrc + (size_t)i * 8 * 1024 + (KT) * 64, &As[BI][(w * 32 + i * 8) * 64]); \
      async16(Bsrc + (size_t)i * 8 * 1024 + (KT) * 64, &Bs[BI][(w * 32 + i * 8) * 64]); \
    }                                                                          \
  }

  G_STAGE(0, 0);
  for (int kt = 0; kt < 16; ++kt) {
    const int cur = kt & 1;
    __syncthreads();
    if (kt < 15) G_STAGE(kt + 1, cur ^ 1);
#pragma unroll
    for (int kk = 0; kk < 2; ++kk) {
      const int kg = kk * 4 + (ln >> 4);
      hfx8 af[4], bfr[4];
#pragma unroll
      for (int mi = 0; mi < 4; ++mi) {
        int row = wr * 64 + mi * 16 + (ln & 15);
        af[mi] = *(const hfx8*)&As[cur][row * 64 + ((kg ^ (row & 7)) * 8)];
      }
#pragma unroll
      for (int ni = 0; ni < 4; ++ni) {
        int row = wc * 64 + ni * 16 + (ln & 15);
        bfr[ni] = *(const hfx8*)&Bs[cur][row * 64 + ((kg ^ (row & 7)) * 8)];
      }
#pragma unroll
      for (int mi = 0; mi < 4; ++mi)
#pragma unroll
        for (int ni = 0; ni < 4; ++ni)
          acc[mi][ni] = __builtin_amdgcn_mfma_f32_16x16x32_f16(af[mi], bfr[ni], acc[mi][ni], 0, 0, 0);
    }
  }
#undef G_STAGE
  const int cb = n0 + wc * 64 + (ln & 15);
  const int rb = m0 + wr * 64 + ((ln >> 4) << 2);
#pragma unroll
  for (int mi = 0; mi < 4; ++mi)
#pragma unroll
    for (int ni = 0; ni < 4; ++ni)
#pragma unroll
      for (int j = 0; j < 4; ++j)
        O[(size_t)(rb + mi * 16 + j) * 1024 + cb + ni * 16] = acc[mi][ni][j];
}

// Flash attention fp16 on 32x32x16 MFMA. block = (qt,h,b); 8 waves x 32 q = 256 q.
// Swapped QK^T: C[key][q], q = lane&31. ADDITIVE mask {0,-1e30} as QK C-init
// (mask must precede the max: multiplicative-after-softmax underflows fp16 P).
// P->B-frag: keep pk[jb+2*h5], SEND pk[jb+2*(1-h5)] via shfl_xor(.,32).
__global__ __launch_bounds__(512, 2)
void attn_fwd(const unsigned short* __restrict__ Qf,
              const unsigned short* __restrict__ Kf,
              const unsigned short* __restrict__ Vt,
              const int* __restrict__ mask,
              unsigned short* __restrict__ Ov) {
  __shared__ __align__(16) unsigned short smem[36864];  // 72KB
  unsigned short (*Ks)[8192] = (unsigned short (*)[8192])(smem);          // 2 x 16KB
  unsigned short (*Vs)[8192] = (unsigned short (*)[8192])(smem + 16384);  // 2 x 16KB
  float* mpsF = (float*)(smem + 32768);                                   // 8KB (2048 f32)
  unsigned short* eb = smem;                                              // epilogue reuse

  const int tid = threadIdx.x;
  const int w = tid >> 6, ln = tid & 63;
  const int qt = blockIdx.x, h = blockIdx.y, b = blockIdx.z;
  const int l31 = ln & 31, h5 = ln >> 5;
  const int q = qt * 256 + w * 32 + l31;

  // Q as B-fragments: lane holds Q[q][d = dc*16 + h5*8 + 0..7]
  hfx8 qb[4];
  {
    const unsigned short* qp = Qf + (size_t)(b * 2048 + q) * 1024 + h * 64 + h5 * 8;
    qb[0] = *(const hfx8*)(qp);
    qb[1] = *(const hfx8*)(qp + 16);
    qb[2] = *(const hfx8*)(qp + 32);
    qb[3] = *(const hfx8*)(qp + 48);
  }
  // mask preload as ADDITIVE f32 {0, -1e30}
  {
    const int* mp = mask + b * 2048 + tid * 4;
    fx4 mv;
#pragma unroll
    for (int e = 0; e < 4; ++e) mv[e] = mp[e] ? 0.0f : -1e30f;
    *(fx4*)&mpsF[tid * 4] = mv;
  }

  fx16 o0 = {}, o1 = {};
  float mrow = -INFINITY, lrow = 0.f;

  // Staging: K chunk = 8 rows x 64d (lane: row +=ln>>3, slot ln&7);
  //          V chunk = 4 rows x 128s (lane: row +=ln>>4, slot ln&15). Swizzle ^= (row&7).
#define A_STAGE(KT, BI)                                                          \
  {                                                                              \
    _Pragma("unroll") for (int ii = 0; ii < 2; ++ii) {                           \
      int krow = w * 16 + ii * 8 + (ln >> 3);                                    \
      async16(Kf + ((size_t)(b * 2048 + (KT) * 128 + krow)) * 1024 + h * 64 +    \
                  (((ln & 7) ^ (ln >> 3)) * 8),                                  \
              &Ks[BI][(w * 2 + ii) * 512]);                                      \
      int vrow = w * 8 + ii * 4 + (ln >> 4);                                     \
      async16(Vt + ((size_t)((b * 16 + h) * 64 + vrow)) * 2048 + (KT) * 128 +    \
                  (((ln & 15) ^ (ii * 4 + (ln >> 4))) * 8),                      \
              &Vs[BI][(w * 2 + ii) * 512]);                                      \
    }                                                                            \
  }

  A_STAGE(0, 0);
  for (int kt = 0; kt < 16; ++kt) {
    const int cur = kt & 1;
    __syncthreads();
    if (kt < 15) A_STAGE(kt + 1, cur ^ 1);

    // QK: s[kb] C[key = kb*32 + crow(reg,h5)][q = l31]; C-init = additive mask
    fx16 sArr[4];
#pragma unroll
    for (int kb = 0; kb < 4; ++kb) {
      fx16 z;
#pragma unroll
      for (int A = 0; A < 4; ++A) {
        fx4 m_ = *(const fx4*)&mpsF[kt * 128 + kb * 32 + 8 * A + 4 * h5];
        z[4 * A + 0] = m_[0];
        z[4 * A + 1] = m_[1];
        z[4 * A + 2] = m_[2];
        z[4 * A + 3] = m_[3];
      }
#pragma unroll
      for (int dc = 0; dc < 4; ++dc) {
        int row = kb * 32 + l31;
        int slot = (dc * 2 + h5) ^ (l31 & 7);
        hfx8 a = *(const hfx8*)&Ks[cur][row * 64 + slot * 8];
        z = __builtin_amdgcn_mfma_f32_32x32x16_f16(a, qb[dc], z, 0, 0, 0);
      }
      sArr[kb] = z;
    }

    // online softmax (per-q state lane-local; partner = lane^32)
    float tm = -INFINITY;
#pragma unroll
    for (int kb = 0; kb < 4; ++kb)
#pragma unroll
      for (int r = 0; r < 16; ++r) tm = fmaxf(tm, sArr[kb][r]);
    tm = fmaxf(tm, __shfl_xor(tm, 32));
    if (!__all(tm <= mrow + 8.0f)) {
      float mn = fmaxf(mrow, tm);
      float fac = exp2f((mrow - mn) * LOG2E);
      mrow = mn;
      lrow *= fac;
#pragma unroll
      for (int r = 0; r < 16; ++r) { o0[r] *= fac; o1[r] *= fac; }
    }
    const float nm2 = -mrow * LOG2E;
    float psum = 0.f;
    unsigned int pk[4][8];
#pragma unroll
    for (int kb = 0; kb < 4; ++kb) {
#pragma unroll
      for (int j = 0; j < 8; ++j) {
        float pa = exp2f(fmaf(sArr[kb][2 * j], LOG2E, nm2));
        float pb = exp2f(fmaf(sArr[kb][2 * j + 1], LOG2E, nm2));
        psum += pa + pb;
        union { fp16x2 h; unsigned int u; } rr;
        rr.h = __builtin_amdgcn_cvt_pkrtz(pa, pb);
        pk[kb][j] = rr.u;
      }
    }
    psum += __shfl_xor(psum, 32);
    lrow += psum;

    // PV: O^T[d][q] += V^T x P^T.
    // Dest half H needs pk[jb+2H], pk[jb+2H+1] from BOTH halves (jb = 4*(kc&1)).
    // Keep own pk[jb+2H]; SEND pk[jb+2(1-H)] so partner receives its index.
#pragma unroll
    for (int kc = 0; kc < 8; ++kc) {
      const int kbq = kc >> 1;
      const int jb = (kc & 1) * 4;
      unsigned int s00 = pk[kbq][jb],     s01 = pk[kbq][jb + 1];  // j = jb   (H=0 pair)
      unsigned int s10 = pk[kbq][jb + 2], s11 = pk[kbq][jb + 3];  // j = jb+2 (H=1 pair)
      unsigned int keep0 = h5 ? s10 : s00, keep1 = h5 ? s11 : s01;
      unsigned int send0 = h5 ? s00 : s10, send1 = h5 ? s01 : s11;
      unsigned int rec0 = (unsigned int)__shfl_xor((int)send0, 32);
      unsigned int rec1 = (unsigned int)__shfl_xor((int)send1, 32);
      union { unsigned int u[4]; hfx8 v; } B_;
      B_.u[0] = h5 ? rec0 : keep0;   // keys i=0..3 (from h5src=0)
      B_.u[1] = h5 ? rec1 : keep1;
      B_.u[2] = h5 ? keep0 : rec0;   // keys i=4..7 (from h5src=1)
      B_.u[3] = h5 ? keep1 : rec1;
      int slot = (kc * 2 + h5) ^ (l31 & 7);
      hfx8 va0 = *(const hfx8*)&Vs[cur][(l31) * 128 + slot * 8];
      o0 = __builtin_amdgcn_mfma_f32_32x32x16_f16(va0, B_.v, o0, 0, 0, 0);
      hfx8 va1 = *(const hfx8*)&Vs[cur][(32 + l31) * 128 + slot * 8];
      o1 = __builtin_amdgcn_mfma_f32_32x32x16_f16(va1, B_.v, o1, 0, 0, 0);
    }
  }
#undef A_STAGE

  // epilogue: divide, transpose via LDS (rows padded to 88 u16 = 176B, 16B-aligned),
  // coalesced store to Av[q][h*64+d]
  __syncthreads();  // all waves done reading K/V LDS before overwrite
  float inv = 1.0f / lrow;
  const int ql = w * 32 + l31;
#pragma unroll
  for (int db = 0; db < 2; ++db) {
#pragma unroll
    for (int r4 = 0; r4 < 4; ++r4) {
      float v0 = (db ? o1[4 * r4] : o0[4 * r4]) * inv;
      float v1 = (db ? o1[4 * r4 + 1] : o0[4 * r4 + 1]) * inv;
      float v2 = (db ? o1[4 * r4 + 2] : o0[4 * r4 + 2]) * inv;
      float v3 = (db ? o1[4 * r4 + 3] : o0[4 * r4 + 3]) * inv;
      union { fp16x2 h; unsigned int u; } pa_, pb_;
      pa_.h = __builtin_amdgcn_cvt_pkrtz(v0, v1);
      pb_.h = __builtin_amdgcn_cvt_pkrtz(v2, v3);
      ux2 tw; tw[0] = pa_.u; tw[1] = pb_.u;
      int d_base = db * 32 + 8 * r4 + 4 * h5;
      *(ux2*)&eb[ql * 88 + d_base] = tw;
    }
  }
  __syncthreads();
#pragma unroll
  for (int pass = 0; pass < 4; ++pass) {
    int idx = pass * 512 + tid;
    int qq = idx >> 3, slot = idx & 7;
    usx8 vv = *(const usx8*)&eb[qq * 88 + slot * 8];
    *(usx8*)&Ov[(size_t)(b * 2048 + qt * 256 + qq) * 1024 + h * 64 + slot * 8] = vv;
  }
}

// out = LayerNorm(h + attn_out) * g + b ; one block per row
__global__ __launch_bounds__(256)
void lnk(const float* __restrict__ h, const float* __restrict__ ao,
         const float* __restrict__ g, const float* __restrict__ bb,
         float* __restrict__ out) {
  const int row = blockIdx.x;
  const int tid = threadIdx.x;
  const size_t base = (size_t)row * 1024 + tid * 4;
  fx4 x = *(const fx4*)(h + base);
  fx4 a = *(const fx4*)(ao + base);
  x = x + a;
  float s = x[0] + x[1] + x[2] + x[3];
  float q = x[0] * x[0] + x[1] * x[1] + x[2] * x[2] + x[3] * x[3];
#pragma unroll
  for (int mm = 1; mm < 64; mm <<= 1) {
    s += __shfl_xor(s, mm);
    q += __shfl_xor(q, mm);
  }
  __shared__ float rs[4], rq[4];
  if ((tid & 63) == 0) { rs[tid >> 6] = s; rq[tid >> 6] = q; }
  __syncthreads();
  s = rs[0] + rs[1] + rs[2] + rs[3];
  q = rq[0] + rq[1] + rq[2] + rq[3];
  float mu = s * (1.0f / 1024.0f);
  float var = q * (1.0f / 1024.0f) - mu * mu;
  float rstd = rsqrtf(var + 1e-5f);
  fx4 gg = *(const fx4*)(g + tid * 4);
  fx4 bv = *(const fx4*)(bb + tid * 4);
  fx4 ov;
#pragma unroll
  for (int k = 0; k < 4; ++k) ov[k] = (x[k] - mu) * rstd * gg[k] + bv[k];
  *(fx4*)(out + base) = ov;
}

extern "C" void kernel_launch(void* const* d_in, const int* in_sizes, int n_in,
                              void* d_out, int out_size, void* d_ws, size_t ws_size,
                              hipStream_t stream) {
  const float* h = (const float*)d_in[0];
  const int* msk = (const int*)d_in[1];
  const float* qw = (const float*)d_in[2];
  const float* kw = (const float*)d_in[3];
  const float* vw = (const float*)d_in[4];
  const float* ow = (const float*)d_in[5];
  const float* lng = (const float*)d_in[6];
  const float* lnb = (const float*)d_in[7];
  float* out = (float*)d_out;
  char* ws = (char*)d_ws;

  const size_t MB = 1u << 20;
  unsigned short* h16 = (unsigned short*)(ws + 0 * MB);   // 8 MB
  unsigned short* w16q = (unsigned short*)(ws + 8 * MB);  // 2 MB
  unsigned short* w16k = (unsigned short*)(ws + 10 * MB); // 2 MB
  unsigned short* w16v = (unsigned short*)(ws + 12 * MB); // 2 MB
  unsigned short* w16o = (unsigned short*)(ws + 14 * MB); // 2 MB
  unsigned short* Qf  = (unsigned short*)(ws + 16 * MB);  // 8 MB
  unsigned short* Kf  = (unsigned short*)(ws + 24 * MB);  // 8 MB
  unsigned short* Vtb = (unsigned short*)(ws + 32 * MB);  // 8 MB
  unsigned short* Av  = (unsigned short*)(ws + 40 * MB);  // 8 MB
  float* Ao = (float*)(ws + 48 * MB);                     // 16 MB

  cvth<<<dim3(4096), 256, 0, stream>>>(h, h16);
  cvtw<<<dim3(1024, 4), 256, 0, stream>>>(qw, kw, vw, ow, w16q, w16k, w16v, w16o);

  gemm_qkv<<<dim3(32, 24), 256, 0, stream>>>(h16, w16q, w16k, w16v, Qf, Kf, Vtb);
  attn_fwd<<<dim3(8, 16, 2), 512, 0, stream>>>(Qf, Kf, Vtb, msk, Av);
  gemm_o<<<dim3(32, 8), 256, 0, stream>>>(Av, w16o, Ao);
  lnk<<<dim3(4096), 256, 0, stream>>>(h, Ao, lng, lnb, out);
}